// Round 6
// baseline (3001.513 us; speedup 1.0000x reference)
//
#include <hip/hip_runtime.h>

// GRU + linear readout, B=128 T=2048 IN=32 H=256 L=16.
// One block per batch row (128 blocks), 1024 threads = 16 waves, 1 block/CU.
// Designed to the REAL 128-VGPR/wave budget (rounds 2-5 evidence): wave w owns
// gate-matched tiles {w, 16+w, 32+w} (r,z,n for h-columns [16w,16w+16)), with
// Whh k-tiles 0..6 in regs (84 VGPR/lane) and k-tile 7 + Wih streamed from
// LDS (conflict-free chunk-major). Gates wave-local from MFMA accumulators
// (batch dim padded 1->16, A rows broadcast-identical). ONE barrier/step,
// double-buffered h (2x256 f16) in LDS, x_t fragment prefetched in regs.

typedef _Float16 half8 __attribute__((ext_vector_type(8)));
typedef float float4v __attribute__((ext_vector_type(4)));

#define TT 2048
#define LOG2E 1.44269504088896f

__device__ __forceinline__ float sigm(float x) {
    return __builtin_amdgcn_rcpf(1.f + __builtin_amdgcn_exp2f(-LOG2E * x));
}
__device__ __forceinline__ float tanhf_(float x) {
    float e = __builtin_amdgcn_exp2f(2.f * LOG2E * x);   // inf-safe: ->1 / ->-1
    return 1.f - 2.f * __builtin_amdgcn_rcpf(e + 1.f);
}

__launch_bounds__(1024)
__global__ void gru_kernel(const float* __restrict__ xg,    // [B,T,32]
                           const float* __restrict__ xlin,  // [B,T,16]
                           const float* __restrict__ h0,    // [B,256]
                           const float* __restrict__ Wih,   // [768,32]
                           const float* __restrict__ Whh,   // [768,256]
                           const float* __restrict__ bias,  // [768]
                           const float* __restrict__ biasn, // [256]
                           float* __restrict__ out)         // [B*T]
{
    __shared__ _Float16 ldsW[24576];     // 48 KB: Whh k-tile 7 (k=224..255)
                                         // chunk-major: byte = qc*12288 + row*16
    __shared__ _Float16 ldsWx[24576];    // 48 KB: Wih, [gtile][lhi][l15] 16B chunks
    __shared__ _Float16 ldsH[2][256];    // double-buffered hidden state

    const int tid  = threadIdx.x;
    const int b    = blockIdx.x;
    const int lane = tid & 63;
    const int w    = tid >> 6;      // wave 0..15
    const int l15  = lane & 15;
    const int lhi  = lane >> 4;     // 0..3 (k-chunk)

    // ---- Whh k-tiles 0..6 -> registers (f16 RTN); wave w tiles {w,16+w,32+w}
    half8 Wh[3][7];
#pragma unroll
    for (int nt = 0; nt < 3; ++nt) {
        const int row = (nt * 16 + w) * 16 + l15;
#pragma unroll
        for (int kt = 0; kt < 7; ++kt) {
            const float4v* pp = (const float4v*)(Whh + row * 256 + kt * 32 + lhi * 8);
            float4v u = pp[0], v2 = pp[1];
            half8 hv;
#pragma unroll
            for (int j = 0; j < 4; ++j) { hv[j] = (_Float16)u[j]; hv[4 + j] = (_Float16)v2[j]; }
            Wh[nt][kt] = hv;
        }
    }

    // ---- Whh k-tile 7 -> LDS, chunk-major, every byte written exactly once
    for (int c = tid; c < 3072; c += 1024) {       // 768 rows * 4 chunks
        const int n = c >> 2, qc = c & 3;
        const float* p = Whh + n * 256 + 224 + qc * 8;
        half8 v;
#pragma unroll
        for (int j = 0; j < 8; ++j) v[j] = (_Float16)p[j];
        *(half8*)((char*)ldsW + qc * 12288 + n * 16) = v;
    }
    // ---- Wih -> LDS; per-tile fragment read is 1024B contiguous
    for (int c = tid; c < 3072; c += 1024) {       // 768 rows * 4 k-chunks
        const int row = c >> 2, qc = c & 3;
        const float* p = Wih + row * 32 + qc * 8;
        half8 v;
#pragma unroll
        for (int j = 0; j < 8; ++j) v[j] = (_Float16)p[j];
        *(half8*)((char*)ldsWx + (((row >> 4) * 64) + qc * 16 + (row & 15)) * 16) = v;
    }

    // ---- biases + hidden state for this wave's 16 columns
    const int col = w * 16 + l15;
    const float b_r = bias[col];
    const float b_z = bias[256 + col];
    const float b_i = bias[512 + col];
    const float b_n = biasn[col];
    float hreg = h0[b * 256 + col];
    if (tid < 256) ldsH[0][tid] = (_Float16)h0[b * 256 + tid];

    // ---- x_0 fragment into registers
    const float* xgb = xg + (size_t)b * TT * 32;
    half8 ax;
    {
        const float4v* px = (const float4v*)(xgb + lhi * 8);
        float4v u = px[0], v2 = px[1];
#pragma unroll
        for (int j = 0; j < 4; ++j) { ax[j] = (_Float16)u[j]; ax[4 + j] = (_Float16)v2[j]; }
    }
    float xlc = 0.f;
    if (w == 0 && lane < 16) xlc = xlin[(size_t)b * TT * 16 + lane];

    __syncthreads();

    // LDS read bases (per-lane); per-tile deltas are compile-time immediates
    const int wxb = w * 1024 + lhi * 256 + l15 * 16;          // ldsWx: +16384/tile
    const int wb  = lhi * 12288 + w * 256 + l15 * 16;         // ldsW:  +4096/tile
    const float4v zero4 = {0.f, 0.f, 0.f, 0.f};

#pragma clang loop unroll(disable)
    for (int t = 0; t < TT; ++t) {
        const int p  = t & 1;
        const int tn = (t < TT - 1) ? t + 1 : t;

        // prefetch next-step inputs (latency hidden under MFMAs)
        const float4v* px = (const float4v*)(xgb + (size_t)tn * 32 + lhi * 8);
        float4v xa = px[0], xb2 = px[1];
        float xln = 0.f;
        if (w == 0 && lane < 16) xln = xlin[((size_t)b * TT + tn) * 16 + lane];

        // ---- x-side MFMAs (K=32=IN): seed r/z accs; n-gate x-part separate
        float4v acc[3];
        float xn;
#pragma unroll
        for (int nt = 0; nt < 3; ++nt) {
            half8 wx = *(const half8*)((const char*)ldsWx + wxb + nt * 16384);
            float4v xq = __builtin_amdgcn_mfma_f32_16x16x32_f16(ax, wx, zero4, 0, 0, 0);
            if (nt == 2) { xn = xq[0]; acc[2] = zero4; }
            else         { acc[nt] = xq; }
        }
        // ---- h-side MFMAs over 8 k-tiles (kt 0..6 regs, kt 7 LDS)
#pragma unroll
        for (int kt = 0; kt < 8; ++kt) {
            half8 a = ((const half8*)ldsH[p])[kt * 4 + lhi];   // broadcast h fragment
#pragma unroll
            for (int nt = 0; nt < 3; ++nt) {
                half8 bb;
                if (kt < 7) bb = Wh[nt][kt];
                else        bb = *(const half8*)((const char*)ldsW + wb + nt * 4096);
                acc[nt] = __builtin_amdgcn_mfma_f32_16x16x32_f16(a, bb, acc[nt], 0, 0, 0);
            }
        }

        // ---- gates: wave-local, straight from accumulators (rows identical)
        {
            float r = sigm(acc[0][0] + b_r);
            float z = sigm(acc[1][0] + b_z);
            float n = tanhf_(xn + b_i + r * (acc[2][0] + b_n));
            float hnew = n + z * (hreg - n);
            hreg = hnew;
            if (lane < 16) ldsH[p ^ 1][col] = (_Float16)hnew;
        }

        // ---- readout: columns 0..15 live in wave 0
        if (w == 0) {
            float v = hreg * xlc;
            v += __shfl_xor(v, 8, 16);
            v += __shfl_xor(v, 4, 16);
            v += __shfl_xor(v, 2, 16);
            v += __shfl_xor(v, 1, 16);
            if (lane == 0) out[(size_t)b * TT + t] = v;
        }

        // ---- commit prefetched x for next step
#pragma unroll
        for (int j = 0; j < 4; ++j) { ax[j] = (_Float16)xa[j]; ax[4 + j] = (_Float16)xb2[j]; }
        xlc = xln;
        __syncthreads();   // new h visible; old buffer free
    }
}

extern "C" void kernel_launch(void* const* d_in, const int* in_sizes, int n_in,
                              void* d_out, int out_size, void* d_ws, size_t ws_size,
                              hipStream_t stream) {
    const float* xg    = (const float*)d_in[0];
    const float* xlin  = (const float*)d_in[1];
    const float* h0    = (const float*)d_in[2];
    const float* Wih   = (const float*)d_in[3];
    const float* Whh   = (const float*)d_in[4];
    const float* bias  = (const float*)d_in[5];
    const float* biasn = (const float*)d_in[6];
    float* out = (float*)d_out;

    gru_kernel<<<128, 1024, 0, stream>>>(xg, xlin, h0, Wih, Whh, bias, biasn, out);
}